// Round 13
// baseline (255.310 us; speedup 1.0000x reference)
//
#include <hip/hip_runtime.h>
#include <math.h>

#define NB 8192
#define NIN 64
#define NOUT 128
#define NHID 32
#define NEXO 3
#define EXROWS 192
#define NTGT 2

typedef float f32x2 __attribute__((ext_vector_type(2)));
typedef float f32x4 __attribute__((ext_vector_type(4)));
typedef short bf16x8 __attribute__((ext_vector_type(8)));

__device__ __forceinline__ float sigmoidf(float x) {
    return 1.0f / (1.0f + __expf(-x));
}

__device__ __forceinline__ unsigned short f2bf(float x) {   // RNE float->bf16
    unsigned int u = __float_as_uint(x);
    unsigned int r = u + 0x7fffu + ((u >> 16) & 1u);
    return (unsigned short)(r >> 16);
}

// packed fp32 FMA, src0 word-broadcast from a pair (par selects lo/hi word).
// ALL sources must be 64-bit register pairs.
__device__ __forceinline__ void pk_fma_bc(f32x2& acc, f32x2 wpair, int par, f32x2 y2) {
    if (par == 0)
        asm("v_pk_fma_f32 %0, %1, %2, %0 op_sel:[0,0,0] op_sel_hi:[0,1,1]"
            : "+v"(acc) : "v"(wpair), "v"(y2));
    else
        asm("v_pk_fma_f32 %0, %1, %2, %0 op_sel:[1,0,0] op_sel_hi:[1,1,1]"
            : "+v"(acc) : "v"(wpair), "v"(y2));
}

// DPP-based cross-lane add (VALU pipe).
template<int CTRL>
__device__ __forceinline__ float dpp_add(float x) {
    int p = __builtin_amdgcn_update_dpp(0, __float_as_int(x), CTRL, 0xf, 0xf, true);
    return x + __int_as_float(p);
}
__device__ __forceinline__ float swz_add_xor16(float x) {   // ds_swizzle xor16
    int p = __builtin_amdgcn_ds_swizzle(__float_as_int(x), 0x401f);
    return x + __int_as_float(p);
}

// -------------------------------------------------------------------------
// Kernel A (MFMA): E[b,i,o] = b1+b3 + out1_exog + out2_exog, written to out.
// (unchanged from rounds 5-10)
// -------------------------------------------------------------------------
__global__ __launch_bounds__(256, 4) void narx_exog_kernel(
    const float* __restrict__ exog,
    const float* __restrict__ W1, const float* __restrict__ b1,
    const float* __restrict__ W2, const float* __restrict__ b2,
    const float* __restrict__ W3, const float* __restrict__ b3,
    float* __restrict__ E)
{
    __shared__ __align__(16) float exs[NEXO][EXROWS];
    __shared__ __align__(16) unsigned short exrep[NEXO * 8][200];
    __shared__ __align__(16) unsigned short w2bf[NEXO * 32][72];
    __shared__ __align__(16) float2 w1e2[NEXO][NIN];
    __shared__ __align__(16) float b2l[96];
    __shared__ __align__(16) float w3l[2][96];

    const int tid = threadIdx.x;
    const int b = blockIdx.x;
    const float* exb = exog + (size_t)b * (EXROWS * NEXO);

    for (int idx = tid; idx < EXROWS * NEXO; idx += 256) {
        int t = idx / 3;
        int e = idx - t * 3;
        exs[e][t] = exb[idx];
    }
    for (int idx = tid; idx < 6144; idx += 256) {
        int e = idx >> 11;
        int rem = idx & 2047;
        int u = rem >> 6, t = rem & 63;
        w2bf[e * 32 + u][t] = f2bf(W2[(size_t)(64 + e * 32 + u) * NIN + t]);
    }
    for (int idx = tid; idx < 192; idx += 256) {
        int e = idx >> 6, t = idx & 63;
        w1e2[e][t] = make_float2(W1[t * 5 + 2 + e], W1[320 + t * 5 + 2 + e]);
    }
    if (tid < 96)  b2l[tid] = b2[64 + tid];
    for (int idx = tid; idx < 192; idx += 256) {
        int o = idx / 96, u = idx - o * 96;
        w3l[o][u] = W3[o * 160 + 64 + u];
    }
    __syncthreads();

    for (int idx = tid; idx < NEXO * 8 * 192; idx += 256) {
        int e = idx / 1536;
        int rem = idx - e * 1536;
        int r = rem / 192;
        int q = rem - r * 192;
        float v = (q + r < 192) ? exs[e][q + r] : 0.f;
        exrep[e * 8 + r][q] = f2bf(v);
    }
    __syncthreads();

    const int wv = tid >> 6;
    const int l  = tid & 63;
    const int iw = wv * 32;
    const int lg = l >> 4;
    const int col = l & 15;

    float acc0[2] = {0.f, 0.f};
    float acc1[2] = {0.f, 0.f};

    #pragma unroll 1
    for (int e = 0; e < NEXO; ++e) {
        f32x4 b2v[2], w30v[2], w31v[2];
        #pragma unroll
        for (int mt = 0; mt < 2; ++mt) {
            b2v[mt]  = *(const f32x4*)&b2l[e * 32 + mt * 16 + lg * 4];
            w30v[mt] = *(const f32x4*)&w3l[0][e * 32 + mt * 16 + lg * 4];
            w31v[mt] = *(const f32x4*)&w3l[1][e * 32 + mt * 16 + lg * 4];
        }

        f32x4 cacc[2][2];
        #pragma unroll
        for (int mt = 0; mt < 2; ++mt)
            #pragma unroll
            for (int nt = 0; nt < 2; ++nt)
                cacc[mt][nt] = b2v[mt];

        #pragma unroll
        for (int kt = 0; kt < 2; ++kt) {
            bf16x8 af[2], bfr[2];
            #pragma unroll
            for (int mt = 0; mt < 2; ++mt)
                af[mt] = *(const bf16x8*)&w2bf[e * 32 + mt * 16 + col][kt * 32 + lg * 8];
            #pragma unroll
            for (int nt = 0; nt < 2; ++nt)
                bfr[nt] = *(const bf16x8*)&exrep[e * 8 + (l & 7)]
                              [iw + nt * 16 + kt * 32 + lg * 8 + ((l >> 3) & 1) * 8];
            #pragma unroll
            for (int mt = 0; mt < 2; ++mt)
                #pragma unroll
                for (int nt = 0; nt < 2; ++nt)
                    cacc[mt][nt] = __builtin_amdgcn_mfma_f32_16x16x32_bf16(
                        af[mt], bfr[nt], cacc[mt][nt], 0, 0, 0);
        }

        #pragma unroll
        for (int mt = 0; mt < 2; ++mt)
            #pragma unroll
            for (int nt = 0; nt < 2; ++nt) {
                #pragma unroll
                for (int r = 0; r < 4; ++r) {
                    float sg = sigmoidf(cacc[mt][nt][r]);
                    acc0[nt] += w30v[mt][r] * sg;
                    acc1[nt] += w31v[mt][r] * sg;
                }
            }

        const float* exs_e = &exs[e][0];
        #pragma unroll
        for (int dt = 0; dt < 16; ++dt) {
            float2 wv2 = w1e2[e][lg * 16 + dt];
            float x0 = exs_e[iw + l + dt];
            float x1 = exs_e[iw + 16 + l + dt];
            acc0[0] += wv2.x * x0;
            acc1[0] += wv2.y * x0;
            acc0[1] += wv2.x * x1;
            acc1[1] += wv2.y * x1;
        }
    }

    #pragma unroll
    for (int nt = 0; nt < 2; ++nt) {
        acc0[nt] += __shfl_xor(acc0[nt], 16, 64);
        acc0[nt] += __shfl_xor(acc0[nt], 32, 64);
        acc1[nt] += __shfl_xor(acc1[nt], 16, 64);
        acc1[nt] += __shfl_xor(acc1[nt], 32, 64);
    }
    if (lg == 0) {
        const float bias0 = b1[0] + b3[0];
        const float bias1 = b1[1] + b3[1];
        #pragma unroll
        for (int nt = 0; nt < 2; ++nt) {
            int i = iw + nt * 16 + col;
            *(float2*)&E[(size_t)b * (NOUT * NTGT) + i * 2] =
                make_float2(acc0[nt] + bias0, acc1[nt] + bias1);
        }
    }
}

// -------------------------------------------------------------------------
// Kernel B v13: r10's proven step core + the register-pressure levers.
// 256-thr block = 4 independent waves, each one batch-pair (f32x2).
// W2 taps in block-shared LDS [tap-pair][unit] (frees ~48 regs). Static dot
// streams rows through an 8-deep reg ring. Steps use DIRECT LDS y1 reads
// (fresh rows written by h==0 at earlier steps, within-wave ordered — the
// r10 pattern that passed post-timing). One barrier total.
// -------------------------------------------------------------------------
#define CH 8
#define NCH 16

__global__ __launch_bounds__(256, 2) void narx_recur_kernel(
    const float* __restrict__ target,
    const float* __restrict__ W1,
    const float* __restrict__ W2, const float* __restrict__ b2,
    const float* __restrict__ W3,
    float* __restrict__ out)
{
    __shared__ __align__(16) f32x2 w2l[32][64];        // [tap-pair][unit], 16 KB
    __shared__ __align__(16) f32x2 yw[4][NTGT][192];   // per-wave window, 12 KB
    __shared__ __align__(16) f32x2 ew[4][NTGT][NOUT];  // per-wave E, 8 KB

    const int tid = threadIdx.x;
    const int w   = tid >> 6;
    const int l   = tid & 63;
    const int s   = l >> 5;
    const int h   = l & 31;
    const size_t bA = ((size_t)blockIdx.x * 4 + w) * 2;
    const size_t bB = bA + 1;

    // ---- stage W2 taps (target units 0..63) ----
    for (int idx = tid; idx < 2048; idx += 256) {
        int t2 = idx >> 6, u = idx & 63;
        const float* p = W2 + (size_t)u * NIN + t2 * 2;
        w2l[t2][u] = f32x2{p[0], p[1]};
    }
    {   // E -> LDS (lane covers rows 2l, 2l+1)
        float4 eA = *(const float4*)&out[bA * (NOUT * NTGT) + l * 4];
        float4 eB = *(const float4*)&out[bB * (NOUT * NTGT) + l * 4];
        ew[w][0][2 * l]     = f32x2{eA.x, eB.x};
        ew[w][1][2 * l]     = f32x2{eA.y, eB.y};
        ew[w][0][2 * l + 1] = f32x2{eA.z, eB.z};
        ew[w][1][2 * l + 1] = f32x2{eA.w, eB.w};
    }
    {   // initial window rows (lane covers row l)
        float2 tA = *(const float2*)&target[bA * (NIN * NTGT) + l * 2];
        float2 tB = *(const float2*)&target[bB * (NIN * NTGT) + l * 2];
        yw[w][0][l] = f32x2{tA.x, tB.x};
        yw[w][1][l] = f32x2{tA.y, tB.y};
    }
    __syncthreads();   // the only barrier

    // ---- per-lane constants ----
    const float bb = b2[l];
    const f32x2 bbp = {bb, bb};
    const f32x2 w3p  = {W3[s * 160 + l], W3[(1 - s) * 160 + l]};        // {own-out, other-out}
    const f32x2 wo1p = {W1[s * 320 + (2 * h) * 5 + s],
                        W1[s * 320 + (2 * h + 1) * 5 + s]};             // own-out taps
    const f32x2 wo2p = {W1[(1 - s) * 320 + (2 * h) * 5 + s],
                        W1[(1 - s) * 320 + (2 * h + 1) * 5 + s]};       // other-out taps
    f32x2 w2tp[4];                  // own-unit taps 57..63 packed as pairs
    {
        const float* wp = W2 + (size_t)l * NIN + 57;
        w2tp[0] = f32x2{wp[0], wp[1]};   // t57, t58
        w2tp[1] = f32x2{wp[2], wp[3]};   // t59, t60
        w2tp[2] = f32x2{wp[4], wp[5]};   // t61, t62
        w2tp[3] = f32x2{wp[6], wp[6]};   // t63, dup
    }

    f32x2* Y = &yw[w][s][0];
    const f32x2* EV = &ew[w][s][0];

    #pragma unroll 1
    for (int c = 0; c < NCH; ++c) {
        const int i0 = c * CH;

        // ---- static dot over known rows: P2[ci] = bb + sum_{t+ci<=63} w2[t]*Y[i0+ci+t] ----
        f32x2 P2[CH];
        #pragma unroll
        for (int j = 0; j < CH; ++j) P2[j] = bbp;
        f32x2 yr[8];
        #pragma unroll
        for (int j = 0; j < 8; ++j) yr[j] = Y[i0 + j];

        #pragma unroll
        for (int t2 = 0; t2 < 32; ++t2) {
            const f32x2 wpair = w2l[t2][l];
            const int t0 = 2 * t2;
            #pragma unroll
            for (int ci = 0; ci < CH; ++ci)
                if (t0 + ci <= 63) pk_fma_bc(P2[ci], wpair, 0, yr[(t0 + ci) & 7]);
            if (t0 + 8 <= 63) yr[t0 & 7] = Y[i0 + t0 + 8];
            const int t1 = t0 + 1;
            #pragma unroll
            for (int ci = 0; ci < CH; ++ci)
                if (t1 + ci <= 63) pk_fma_bc(P2[ci], wpair, 1, yr[(t1 + ci) & 7]);
            if (t1 + 8 <= 63) yr[t1 & 7] = Y[i0 + t1 + 8];
        }

        // ---- 8 sequential steps (r10 core: direct LDS y1 reads) ----
        f32x2 predprev = yr[7];   // row i0+63

        #pragma unroll
        for (int ci = 0; ci < CH; ++ci) {
            const int i = i0 + ci;
            const f32x2 y1a = Y[i + 2 * h];
            const f32x2 y1b = Y[i + 2 * h + 1];
            const f32x2 ev  = EV[i];

            f32x2 sg;
            sg.x = sigmoidf(P2[ci].x);
            sg.y = sigmoidf(P2[ci].y);

            f32x2 va = {0.f, 0.f}, vb = {0.f, 0.f};
            pk_fma_bc(va, w3p, 0, sg);
            pk_fma_bc(vb, w3p, 1, sg);
            pk_fma_bc(va, wo1p, 0, y1a);
            pk_fma_bc(va, wo1p, 1, y1b);
            pk_fma_bc(vb, wo2p, 0, y1a);
            pk_fma_bc(vb, wo2p, 1, y1b);

            // reduce: cross-half fold (VALU) + xor16 (LDS swizzle) + DPP {8,7,2,1}
            auto r0 = __builtin_amdgcn_permlane32_swap(
                __float_as_uint(vb.x), __float_as_uint(vb.x), false, false);
            auto r1 = __builtin_amdgcn_permlane32_swap(
                __float_as_uint(vb.y), __float_as_uint(vb.y), false, false);
            f32x2 cc2;
            cc2.x = va.x + (s ? __uint_as_float(r0[0]) : __uint_as_float(r0[1]));
            cc2.y = va.y + (s ? __uint_as_float(r1[0]) : __uint_as_float(r1[1]));
            cc2.x = swz_add_xor16(cc2.x);  cc2.y = swz_add_xor16(cc2.y);
            cc2.x = dpp_add<0x128>(cc2.x); cc2.y = dpp_add<0x128>(cc2.y);
            cc2.x = dpp_add<0x141>(cc2.x); cc2.y = dpp_add<0x141>(cc2.y);
            cc2.x = dpp_add<0x4E>(cc2.x);  cc2.y = dpp_add<0x4E>(cc2.y);
            cc2.x = dpp_add<0xB1>(cc2.x);  cc2.y = dpp_add<0xB1>(cc2.y);

            const f32x2 pred = cc2 + ev + predprev;

            // recurrent w2 tails for future steps (static indices)
            #pragma unroll
            for (int cj = ci + 1; cj < CH; ++cj) {
                const int d = cj - ci;            // 1..7
                const int j = 7 - d;              // 0..6 -> tap 64-d
                pk_fma_bc(P2[cj], w2tp[j >> 1], j & 1, pred);
            }
            if (h == 0) Y[i + 64] = pred;
            predprev = pred;
        }
    }

    // ---- dump: lane l covers output rows 2l, 2l+1 for both batches ----
    {
        f32x2 a0 = yw[w][0][NIN + 2 * l];
        f32x2 a1 = yw[w][1][NIN + 2 * l];
        f32x2 c0 = yw[w][0][NIN + 2 * l + 1];
        f32x2 c1 = yw[w][1][NIN + 2 * l + 1];
        *(float4*)&out[bA * (NOUT * NTGT) + l * 4] = make_float4(a0.x, a1.x, c0.x, c1.x);
        *(float4*)&out[bB * (NOUT * NTGT) + l * 4] = make_float4(a0.y, a1.y, c0.y, c1.y);
    }
}

extern "C" void kernel_launch(void* const* d_in, const int* in_sizes, int n_in,
                              void* d_out, int out_size, void* d_ws, size_t ws_size,
                              hipStream_t stream) {
    (void)in_sizes; (void)n_in; (void)out_size; (void)d_ws; (void)ws_size;
    const float* target = (const float*)d_in[0];
    const float* exog   = (const float*)d_in[1];
    const float* W1     = (const float*)d_in[2];
    const float* b1     = (const float*)d_in[3];
    const float* W2     = (const float*)d_in[4];
    const float* b2     = (const float*)d_in[5];
    const float* W3     = (const float*)d_in[6];
    const float* b3     = (const float*)d_in[7];
    float* out = (float*)d_out;

    hipLaunchKernelGGL(narx_exog_kernel, dim3(NB), dim3(256), 0, stream,
                       exog, W1, b1, W2, b2, W3, b3, out);
    hipLaunchKernelGGL(narx_recur_kernel, dim3(NB / 8), dim3(256), 0, stream,
                       target, W1, W2, b2, W3, out);
}